// Round 1
// baseline (197.284 us; speedup 1.0000x reference)
//
#include <hip/hip_runtime.h>
#include <hip/hip_bf16.h>
#include <float.h>

#define N_PRED 8192
#define M_TGT  16384
#define KD     128
#define TOPK   5
#define ROWS_PER_BLOCK 32
#define WAVES  8
#define MCHUNK (M_TGT / WAVES)   // 2048 targets per wave

using short8  = __attribute__((ext_vector_type(8))) short;
using floatx4 = __attribute__((ext_vector_type(4))) float;

__device__ __forceinline__ unsigned short f2bf(float v) {
    // round-to-nearest-even fp32 -> bf16 (inputs are finite gaussians; no NaN path needed)
    unsigned int u = __float_as_uint(v);
    u = (u + 0x7FFFu + ((u >> 16) & 1u)) >> 16;
    return (unsigned short)u;
}

// ---------------- prep: cast to bf16 (pred pre-scaled by -2), norms, zero acc ----
__global__ void prep_kernel(const float* __restrict__ pred,
                            const float* __restrict__ tgt,
                            unsigned short* __restrict__ predB,
                            unsigned short* __restrict__ tgtB,
                            float* __restrict__ a2,
                            float* __restrict__ b2,
                            float* __restrict__ acc) {
    const int r = blockIdx.x;
    const int t = threadIdx.x;
    const float* src;
    unsigned short* dst;
    float scale;
    float* norm;
    if (r < N_PRED) {
        src = pred + (size_t)r * KD;
        dst = predB + (size_t)r * KD;
        scale = -2.0f;            // fold the "-2 a.b" into the A operand
        norm = a2 + r;
    } else {
        const int rr = r - N_PRED;
        src = tgt + (size_t)rr * KD;
        dst = tgtB + (size_t)rr * KD;
        scale = 1.0f;
        norm = b2 + rr;
    }
    const float x = src[t];
    dst[t] = f2bf(x * scale);
    float s = x * x;              // norms from ORIGINAL fp32 values
    #pragma unroll
    for (int off = 32; off > 0; off >>= 1) s += __shfl_down(s, off);
    __shared__ float ws[2];
    if ((t & 63) == 0) ws[t >> 6] = s;
    __syncthreads();
    if (t == 0) norm[0] = ws[0] + ws[1];
    if (r == 0 && t == 0) acc[0] = 0.0f;
}

// ---------------- main: MFMA distances + streaming per-lane top-5 of d^2 --------
__global__ __launch_bounds__(512, 1) void density_kernel(
        const unsigned short* __restrict__ predB,
        const unsigned short* __restrict__ tgtB,
        const float* __restrict__ a2,
        const float* __restrict__ b2,
        float* __restrict__ acc) {
    const int tid  = threadIdx.x;
    const int wave = tid >> 6;
    const int lane = tid & 63;
    const int col  = lane & 15;   // MFMA: A-row index for A-frag, C-col (target) in epilogue
    const int quad = lane >> 4;
    const int rowBase = blockIdx.x * ROWS_PER_BLOCK;

    // A fragments: A[m=lane&15][k=quad*8+j] -> contiguous 16B per lane, kept in regs
    short8 afrag[2][4];
    #pragma unroll
    for (int rf = 0; rf < 2; rf++)
        #pragma unroll
        for (int kf = 0; kf < 4; kf++) {
            const unsigned short* p =
                predB + (size_t)(rowBase + rf * 16 + col) * KD + kf * 32 + quad * 8;
            afrag[rf][kf] = *reinterpret_cast<const short8*>(p);
        }

    // a2 for this lane's C rows: row = quad*4 + reg
    float a2r[2][4];
    #pragma unroll
    for (int rf = 0; rf < 2; rf++)
        #pragma unroll
        for (int rg = 0; rg < 4; rg++)
            a2r[rf][rg] = a2[rowBase + rf * 16 + quad * 4 + rg];

    // per-lane top-5 (ascending) of d^2, per C-row
    float t5[2][4][5];
    #pragma unroll
    for (int rf = 0; rf < 2; rf++)
        #pragma unroll
        for (int rg = 0; rg < 4; rg++)
            #pragma unroll
            for (int j = 0; j < 5; j++)
                t5[rf][rg][j] = FLT_MAX;

    const int mBase = wave * MCHUNK;
    const unsigned short* bp = tgtB + (size_t)(mBase + col) * KD + quad * 8;
    const float* b2p = b2 + mBase + col;

    for (int it = 0; it < MCHUNK / 16; ++it) {
        const short8 b0 = *reinterpret_cast<const short8*>(bp);
        const short8 b1 = *reinterpret_cast<const short8*>(bp + 32);
        const short8 bx = *reinterpret_cast<const short8*>(bp + 64);
        const short8 b3 = *reinterpret_cast<const short8*>(bp + 96);
        const float b2c = *b2p;

        #pragma unroll
        for (int rf = 0; rf < 2; rf++) {
            floatx4 c;
            #pragma unroll
            for (int rg = 0; rg < 4; rg++) c[rg] = a2r[rf][rg] + b2c;  // seed with |a|^2+|b|^2
            c = __builtin_amdgcn_mfma_f32_16x16x32_bf16(afrag[rf][0], b0, c, 0, 0, 0);
            c = __builtin_amdgcn_mfma_f32_16x16x32_bf16(afrag[rf][1], b1, c, 0, 0, 0);
            c = __builtin_amdgcn_mfma_f32_16x16x32_bf16(afrag[rf][2], bx, c, 0, 0, 0);
            c = __builtin_amdgcn_mfma_f32_16x16x32_bf16(afrag[rf][3], b3, c, 0, 0, 0);
            // c[rg] is now d^2 (A was pre-scaled by -2). Branchless sorted top-5 insert.
            #pragma unroll
            for (int rg = 0; rg < 4; rg++) {
                const float d = c[rg];
                float* t = t5[rf][rg];
                t[4] = fminf(t[4], fmaxf(t[3], d));
                t[3] = fminf(t[3], fmaxf(t[2], d));
                t[2] = fminf(t[2], fmaxf(t[1], d));
                t[1] = fminf(t[1], fmaxf(t[0], d));
                t[0] = fminf(t[0], d);
            }
        }
        bp  += 16 * KD;
        b2p += 16;
    }

    // ---- in-block merge: 640 candidates per row -> top-5 -> hinge -> atomicAdd --
    __shared__ float sm[16 * 128 * 5];   // 40 KB, reused across the two 16-row passes
    __shared__ float sm2[16 * 16 * 5];   // 5 KB

    for (int rf = 0; rf < 2; rf++) {
        __syncthreads();
        #pragma unroll
        for (int rg = 0; rg < 4; rg++)
            #pragma unroll
            for (int j = 0; j < 5; j++)
                sm[((quad * 4 + rg) * 128 + wave * 16 + col) * 5 + j] = t5[rf][rg][j];
        __syncthreads();
        if (tid < 256) {
            const int r16 = tid >> 4, part = tid & 15;
            float u[5] = {FLT_MAX, FLT_MAX, FLT_MAX, FLT_MAX, FLT_MAX};
            for (int s = 0; s < 8; s++) {
                #pragma unroll
                for (int j = 0; j < 5; j++) {
                    const float d = sm[(r16 * 128 + part * 8 + s) * 5 + j];
                    u[4] = fminf(u[4], fmaxf(u[3], d));
                    u[3] = fminf(u[3], fmaxf(u[2], d));
                    u[2] = fminf(u[2], fmaxf(u[1], d));
                    u[1] = fminf(u[1], fmaxf(u[0], d));
                    u[0] = fminf(u[0], d);
                }
            }
            #pragma unroll
            for (int j = 0; j < 5; j++) sm2[(r16 * 16 + part) * 5 + j] = u[j];
        }
        __syncthreads();
        if (tid < 16) {
            float u[5] = {FLT_MAX, FLT_MAX, FLT_MAX, FLT_MAX, FLT_MAX};
            for (int s = 0; s < 16; s++) {
                #pragma unroll
                for (int j = 0; j < 5; j++) {
                    const float d = sm2[(tid * 16 + s) * 5 + j];
                    u[4] = fminf(u[4], fmaxf(u[3], d));
                    u[3] = fminf(u[3], fmaxf(u[2], d));
                    u[2] = fminf(u[2], fmaxf(u[1], d));
                    u[1] = fminf(u[1], fmaxf(u[0], d));
                    u[0] = fminf(u[0], d);
                }
            }
            float hs = 0.0f;
            #pragma unroll
            for (int j = 0; j < 5; j++) {
                const float dd = sqrtf(fmaxf(u[j], 0.0f));
                hs += fmaxf(dd - 1.0f, 0.0f);
            }
            atomicAdd(acc, hs);
        }
    }
}

// ---------------- finalize ------------------------------------------------------
__global__ void finalize_kernel(const float* __restrict__ acc, float* __restrict__ out) {
    out[0] = acc[0] * (1.0f / (float)(N_PRED * TOPK));
}

extern "C" void kernel_launch(void* const* d_in, const int* in_sizes, int n_in,
                              void* d_out, int out_size, void* d_ws, size_t ws_size,
                              hipStream_t stream) {
    const float* pred = (const float*)d_in[0];
    const float* tgt  = (const float*)d_in[1];
    char* ws = (char*)d_ws;
    // ws layout: predB 2MB | tgtB 4MB | a2 32KB | b2 64KB | acc 4B  (~6.4 MB total)
    unsigned short* predB = (unsigned short*)(ws);
    unsigned short* tgtB  = (unsigned short*)(ws + (size_t)2 * 1024 * 1024);
    float* a2  = (float*)(ws + (size_t)6 * 1024 * 1024);
    float* b2  = (float*)(ws + (size_t)6 * 1024 * 1024 + 32 * 1024);
    float* acc = (float*)(ws + (size_t)6 * 1024 * 1024 + 96 * 1024);
    float* out = (float*)d_out;

    prep_kernel<<<N_PRED + M_TGT, KD, 0, stream>>>(pred, tgt, predB, tgtB, a2, b2, acc);
    density_kernel<<<N_PRED / ROWS_PER_BLOCK, 512, 0, stream>>>(predB, tgtB, a2, b2, acc);
    finalize_kernel<<<1, 1, 0, stream>>>(acc, out);
}